// Round 1
// baseline (356.150 us; speedup 1.0000x reference)
//
#include <hip/hip_runtime.h>

#define HW 262144          // 512*512 pixels per image
#define NBINS 4096         // top-12-bit histogram (sign=0 | 8 exp | 4 mantissa)
#define BPI 8              // blocks per image in kernel 1
#define T1 512             // threads per block, kernel 1
#define POS_THRESH 0.1f
#define FALLBACK_POS 1000.0f

// ---------------------------------------------------------------------------
// Kernel 1: one streaming pass over all 5 input arrays.
// Each block handles a 32768-pixel slice of one image, building LDS
// histograms (count + sum) of the NEGATIVE losses for region and affinity,
// plus a register accumulator for the positive-loss sums. Histograms are
// over the top 12 bits of the f32 bit pattern: monotone in value for v>=0.
// ---------------------------------------------------------------------------
__global__ __launch_bounds__(T1) void maploss_hist(
    const float* __restrict__ rlab, const float* __restrict__ alab,
    const float* __restrict__ rpre, const float* __restrict__ apre,
    const float* __restrict__ mask,
    unsigned int* __restrict__ g_cnt,   // [2*B][NBINS]
    float* __restrict__ g_sum,          // [2*B][NBINS]
    float* __restrict__ g_pos)          // [2*B]
{
    __shared__ unsigned int s_cnt[2][NBINS];  // 32 KB
    __shared__ float        s_sum[2][NBINS];  // 32 KB
    __shared__ float        s_red[2][T1 / 64];

    const int tid   = threadIdx.x;
    const int slice = blockIdx.x;   // 0..BPI-1
    const int img   = blockIdx.y;   // 0..B-1

    for (int i = tid; i < NBINS; i += T1) {
        s_cnt[0][i] = 0u;  s_cnt[1][i] = 0u;
        s_sum[0][i] = 0.f; s_sum[1][i] = 0.f;
    }
    __syncthreads();

    const size_t base = (size_t)img * HW + (size_t)slice * (HW / BPI);
    const float4* rl4 = (const float4*)(rlab + base);
    const float4* al4 = (const float4*)(alab + base);
    const float4* rp4 = (const float4*)(rpre + base);
    const float4* ap4 = (const float4*)(apre + base);
    const float4* m4  = (const float4*)(mask + base);

    float posr = 0.f, posa = 0.f;

    auto proc = [&](float lab, float pre, float mm, int op, float& posacc) {
        float d = pre - lab;
        float l = d * d * mm;                 // loss >= 0 (mask >= 0)
        if (lab > POS_THRESH) {
            posacc += l;
        } else {
            unsigned int b = __float_as_uint(l) >> 19;  // 0..4095 for v>=0,<inf-range we use
            if (b > NBINS - 1) b = NBINS - 1;           // safety clamp
            atomicAdd(&s_cnt[op][b], 1u);
            atomicAdd(&s_sum[op][b], l);
        }
    };

    const int NV = (HW / BPI) / 4;            // 8192 float4 per slice
    for (int idx = tid; idx < NV; idx += T1) {
        float4 rl = rl4[idx], al = al4[idx];
        float4 rp = rp4[idx], ap = ap4[idx];
        float4 m  = m4[idx];
        proc(rl.x, rp.x, m.x, 0, posr);  proc(al.x, ap.x, m.x, 1, posa);
        proc(rl.y, rp.y, m.y, 0, posr);  proc(al.y, ap.y, m.y, 1, posa);
        proc(rl.z, rp.z, m.z, 0, posr);  proc(al.z, ap.z, m.z, 1, posa);
        proc(rl.w, rp.w, m.w, 0, posr);  proc(al.w, ap.w, m.w, 1, posa);
    }
    __syncthreads();

    // Merge nonzero bins into per-image-op global histograms.
    const size_t j0 = (size_t)img * 2;
    for (int i = tid; i < NBINS; i += T1) {
        unsigned int c0 = s_cnt[0][i];
        if (c0) {
            atomicAdd(&g_cnt[j0 * NBINS + i], c0);
            atomicAdd(&g_sum[j0 * NBINS + i], s_sum[0][i]);
        }
        unsigned int c1 = s_cnt[1][i];
        if (c1) {
            atomicAdd(&g_cnt[(j0 + 1) * NBINS + i], c1);
            atomicAdd(&g_sum[(j0 + 1) * NBINS + i], s_sum[1][i]);
        }
    }

    // Block-reduce positive-loss sums (wave shuffle + LDS across waves).
    for (int off = 32; off > 0; off >>= 1) {
        posr += __shfl_down(posr, off);
        posa += __shfl_down(posa, off);
    }
    const int wave = tid >> 6, lane = tid & 63;
    if (lane == 0) { s_red[0][wave] = posr; s_red[1][wave] = posa; }
    __syncthreads();
    if (tid == 0) {
        float pr = 0.f, pa = 0.f;
        for (int w = 0; w < T1 / 64; ++w) { pr += s_red[0][w]; pa += s_red[1][w]; }
        atomicAdd(&g_pos[j0], pr);
        atomicAdd(&g_pos[j0 + 1], pa);
    }
}

// ---------------------------------------------------------------------------
// Kernel 2: per image-op finalize. Top-down scan of the 4096-bin histogram
// to find the top-k crossing; proportional split inside the boundary bin.
// Reproduces the reference's branch structure exactly.
// ---------------------------------------------------------------------------
__global__ __launch_bounds__(256) void maploss_finalize(
    const unsigned int* __restrict__ g_cnt, const float* __restrict__ g_sum,
    const float* __restrict__ g_pos, const int* __restrict__ neg_rto_p,
    float* __restrict__ out, int batch)
{
    const int j   = blockIdx.x;
    const int tid = threadIdx.x;
    __shared__ unsigned int s_ccnt[256];
    __shared__ float        s_csum[256];

    const unsigned int* cnt = g_cnt + (size_t)j * NBINS;
    const float*        sum = g_sum + (size_t)j * NBINS;

    unsigned int c = 0; float s = 0.f;
    #pragma unroll
    for (int i = 0; i < NBINS / 256; ++i) {
        c += cnt[tid * (NBINS / 256) + i];
        s += sum[tid * (NBINS / 256) + i];
    }
    s_ccnt[tid] = c; s_csum[tid] = s;
    __syncthreads();

    if (tid == 0) {
        long long n = 0; double sum_neg = 0.0;
        for (int t = 0; t < 256; ++t) { n += s_ccnt[t]; sum_neg += (double)s_csum[t]; }
        const long long p = (long long)HW - n;

        const float neg_rto = (float)(*neg_rto_p);
        const double pos_loss = (p > 0) ? (double)g_pos[j] / (double)p : 0.0;
        const float  p_eff    = (p > 0) ? (float)p : FALLBACK_POS;
        const float  k_f      = neg_rto * p_eff;
        const long long k     = (long long)floorf(k_f);

        double topk = 0.0;
        if (k > 0) {
            if (n <= k) {
                topk = sum_neg;   // fewer negatives than k: zeros pad the top-k
            } else {
                long long cum = 0; double sacc = 0.0; int chunk = 0;
                for (int t = 255; t >= 0; --t) {
                    if (cum + (long long)s_ccnt[t] >= k) { chunk = t; break; }
                    cum += s_ccnt[t]; sacc += (double)s_csum[t];
                }
                topk = sacc;
                const int cpb = NBINS / 256;
                for (int b = chunk * cpb + cpb - 1; b >= chunk * cpb; --b) {
                    const unsigned int cb = cnt[b];
                    if (cum + (long long)cb >= k) {
                        const long long needed = k - cum;   // 1..cb
                        topk += ((double)needed / (double)cb) * (double)sum[b];
                        break;
                    }
                    cum += cb; topk += (double)sum[b];
                }
            }
        }

        const bool use_all = (p > 0) && ((float)n < k_f);
        double neg_loss;
        if (use_all) {
            const double nd = (n > 0) ? (double)n : 1.0;
            neg_loss = sum_neg / nd;
        } else {
            neg_loss = topk / (double)k_f;
        }
        const double contrib = (pos_loss + neg_loss) / (double)batch;
        atomicAdd(out, (float)contrib);
    }
}

// ---------------------------------------------------------------------------
extern "C" void kernel_launch(void* const* d_in, const int* in_sizes, int n_in,
                              void* d_out, int out_size, void* d_ws, size_t ws_size,
                              hipStream_t stream) {
    const float* rlab = (const float*)d_in[0];
    const float* alab = (const float*)d_in[1];
    const float* rpre = (const float*)d_in[2];
    const float* apre = (const float*)d_in[3];
    const float* mask = (const float*)d_in[4];
    const int*   nrto = (const int*)d_in[5];

    const int B = in_sizes[0] / HW;            // 64
    const int J = 2 * B;                       // image-ops

    unsigned int* g_cnt = (unsigned int*)d_ws;
    float*        g_sum = (float*)((char*)d_ws + (size_t)J * NBINS * sizeof(unsigned int));
    float*        g_pos = (float*)((char*)d_ws + (size_t)J * NBINS * (sizeof(unsigned int) + sizeof(float)));

    const size_t zbytes = (size_t)J * NBINS * (sizeof(unsigned int) + sizeof(float))
                        + (size_t)J * sizeof(float);
    hipMemsetAsync(d_ws, 0, zbytes, stream);
    hipMemsetAsync(d_out, 0, sizeof(float), stream);

    dim3 grid1(BPI, B);
    maploss_hist<<<grid1, T1, 0, stream>>>(rlab, alab, rpre, apre, mask,
                                           g_cnt, g_sum, g_pos);
    maploss_finalize<<<J, 256, 0, stream>>>(g_cnt, g_sum, g_pos, nrto,
                                            (float*)d_out, B);
}

// Round 2
// 316.552 us; speedup vs baseline: 1.1251x; 1.1251x over previous
//
#include <hip/hip_runtime.h>

#define HW 262144          // 512*512 pixels per image
#define NBINS 1024         // 10-bit histogram (8 exp | 2 mantissa), value>=0
#define BPI 32             // blocks per image in kernel 1 (slice = 8192 px)
#define T1 256             // threads per block, kernel 1
#define POS_THRESH 0.1f
#define FALLBACK_POS 1000.0f
#define FIX_SCALE 16777216.0f     // 2^24 fixed-point scale for loss sums
#define INV_FIX   (1.0 / 16777216.0)
#define CNT_SHIFT 44
#define SUM_MASK  ((1ULL << CNT_SHIFT) - 1)

// ---------------------------------------------------------------------------
// Kernel 1: one streaming pass. Per block: 8192-px slice of one image.
// Packed LDS histogram (count<<44 | fixed-point sum) of negative losses for
// region+affinity -> ONE ds_add_u64 per negative pixel-op. 16 KB LDS.
// 2x unrolled loads: 10 float4 in flight per iteration.
// ---------------------------------------------------------------------------
__global__ __launch_bounds__(T1, 5) void maploss_hist(
    const float* __restrict__ rlab, const float* __restrict__ alab,
    const float* __restrict__ rpre, const float* __restrict__ apre,
    const float* __restrict__ mask,
    unsigned long long* __restrict__ g_hist,  // [2*B][NBINS] packed
    float* __restrict__ g_pos)                // [2*B]
{
    __shared__ unsigned long long s_hist[2][NBINS];   // 16 KB
    __shared__ float s_red[2][T1 / 64];

    const int tid   = threadIdx.x;
    const int slice = blockIdx.x;   // 0..BPI-1
    const int img   = blockIdx.y;   // 0..B-1

    for (int i = tid; i < NBINS; i += T1) {
        s_hist[0][i] = 0ull;
        s_hist[1][i] = 0ull;
    }
    __syncthreads();

    const size_t base = (size_t)img * HW + (size_t)slice * (HW / BPI);
    const float4* rl4 = (const float4*)(rlab + base);
    const float4* al4 = (const float4*)(alab + base);
    const float4* rp4 = (const float4*)(rpre + base);
    const float4* ap4 = (const float4*)(apre + base);
    const float4* m4  = (const float4*)(mask + base);

    float posr = 0.f, posa = 0.f;

    auto proc = [&](float lab, float pre, float mm, int op, float& pacc) {
        float d = pre - lab;
        float l = d * d * mm;
        if (lab > POS_THRESH) {
            pacc += l;
        } else {
            unsigned int b = __float_as_uint(l) >> 21;   // monotone for l>=0
            if (b >= NBINS) b = NBINS - 1;               // safety clamp
            unsigned long long pk = (1ULL << CNT_SHIFT) |
                (unsigned long long)(fminf(l, 2.0f) * FIX_SCALE);
            atomicAdd(&s_hist[op][b], pk);
        }
    };

    const int NV = (HW / BPI) / 4;            // 2048 float4 per slice
    for (int i0 = tid; i0 < NV; i0 += 2 * T1) {
        const int i1 = i0 + T1;               // NV = 8*T1 -> always in range
        float4 rl0 = rl4[i0], rl1 = rl4[i1];
        float4 al0 = al4[i0], al1 = al4[i1];
        float4 rp0 = rp4[i0], rp1 = rp4[i1];
        float4 ap0 = ap4[i0], ap1 = ap4[i1];
        float4 m0  = m4[i0],  m1  = m4[i1];

        proc(rl0.x, rp0.x, m0.x, 0, posr);  proc(al0.x, ap0.x, m0.x, 1, posa);
        proc(rl0.y, rp0.y, m0.y, 0, posr);  proc(al0.y, ap0.y, m0.y, 1, posa);
        proc(rl0.z, rp0.z, m0.z, 0, posr);  proc(al0.z, ap0.z, m0.z, 1, posa);
        proc(rl0.w, rp0.w, m0.w, 0, posr);  proc(al0.w, ap0.w, m0.w, 1, posa);

        proc(rl1.x, rp1.x, m1.x, 0, posr);  proc(al1.x, ap1.x, m1.x, 1, posa);
        proc(rl1.y, rp1.y, m1.y, 0, posr);  proc(al1.y, ap1.y, m1.y, 1, posa);
        proc(rl1.z, rp1.z, m1.z, 0, posr);  proc(al1.z, ap1.z, m1.z, 1, posa);
        proc(rl1.w, rp1.w, m1.w, 0, posr);  proc(al1.w, ap1.w, m1.w, 1, posa);
    }
    __syncthreads();

    // Merge nonzero bins into per-image-op global histograms (u64 atomics).
    const size_t j0 = (size_t)img * 2;
    for (int i = tid; i < NBINS; i += T1) {
        unsigned long long v0 = s_hist[0][i];
        if (v0) atomicAdd(&g_hist[j0 * NBINS + i], v0);
        unsigned long long v1 = s_hist[1][i];
        if (v1) atomicAdd(&g_hist[(j0 + 1) * NBINS + i], v1);
    }

    // Block-reduce positive-loss sums.
    for (int off = 32; off > 0; off >>= 1) {
        posr += __shfl_down(posr, off);
        posa += __shfl_down(posa, off);
    }
    const int wave = tid >> 6, lane = tid & 63;
    if (lane == 0) { s_red[0][wave] = posr; s_red[1][wave] = posa; }
    __syncthreads();
    if (tid == 0) {
        float pr = 0.f, pa = 0.f;
        for (int w = 0; w < T1 / 64; ++w) { pr += s_red[0][w]; pa += s_red[1][w]; }
        atomicAdd(&g_pos[j0], pr);
        atomicAdd(&g_pos[j0 + 1], pa);
    }
}

// ---------------------------------------------------------------------------
// Kernel 2: per image-op finalize. Decode packed histogram, top-down scan to
// the top-k crossing, proportional split in the boundary bin. Reproduces the
// reference branch structure exactly.
// ---------------------------------------------------------------------------
__global__ __launch_bounds__(256) void maploss_finalize(
    const unsigned long long* __restrict__ g_hist,
    const float* __restrict__ g_pos, const int* __restrict__ neg_rto_p,
    float* __restrict__ out, int batch)
{
    const int j   = blockIdx.x;
    const int tid = threadIdx.x;
    __shared__ unsigned int s_cc[256];
    __shared__ double       s_cs[256];

    const unsigned long long* h = g_hist + (size_t)j * NBINS;
    const int cpb = NBINS / 256;   // 4 bins per thread

    unsigned int c = 0; double s = 0.0;
    #pragma unroll
    for (int i = 0; i < cpb; ++i) {
        unsigned long long v = h[tid * cpb + i];
        c += (unsigned int)(v >> CNT_SHIFT);
        s += (double)(v & SUM_MASK) * INV_FIX;
    }
    s_cc[tid] = c; s_cs[tid] = s;
    __syncthreads();

    if (tid == 0) {
        long long n = 0; double sum_neg = 0.0;
        for (int t = 0; t < 256; ++t) { n += s_cc[t]; sum_neg += s_cs[t]; }
        const long long p = (long long)HW - n;

        const float neg_rto = (float)(*neg_rto_p);
        const double pos_loss = (p > 0) ? (double)g_pos[j] / (double)p : 0.0;
        const float  p_eff    = (p > 0) ? (float)p : FALLBACK_POS;
        const float  k_f      = neg_rto * p_eff;
        const long long k     = (long long)floorf(k_f);

        double topk = 0.0;
        if (k > 0) {
            if (n <= k) {
                topk = sum_neg;   // zeros pad the top-k beyond n
            } else {
                long long cum = 0; double sacc = 0.0; int chunk = 0;
                for (int t = 255; t >= 0; --t) {
                    if (cum + (long long)s_cc[t] >= k) { chunk = t; break; }
                    cum += s_cc[t]; sacc += s_cs[t];
                }
                topk = sacc;
                for (int b = chunk * cpb + cpb - 1; b >= chunk * cpb; --b) {
                    unsigned long long v = h[b];
                    const long long cb = (long long)(v >> CNT_SHIFT);
                    const double    sb = (double)(v & SUM_MASK) * INV_FIX;
                    if (cum + cb >= k) {
                        const long long needed = k - cum;   // 1..cb
                        topk += ((double)needed / (double)cb) * sb;
                        break;
                    }
                    cum += cb; topk += sb;
                }
            }
        }

        const bool use_all = (p > 0) && ((float)n < k_f);
        double neg_loss;
        if (use_all) {
            const double nd = (n > 0) ? (double)n : 1.0;
            neg_loss = sum_neg / nd;
        } else {
            neg_loss = topk / (double)k_f;
        }
        const double contrib = (pos_loss + neg_loss) / (double)batch;
        atomicAdd(out, (float)contrib);
    }
}

// ---------------------------------------------------------------------------
extern "C" void kernel_launch(void* const* d_in, const int* in_sizes, int n_in,
                              void* d_out, int out_size, void* d_ws, size_t ws_size,
                              hipStream_t stream) {
    const float* rlab = (const float*)d_in[0];
    const float* alab = (const float*)d_in[1];
    const float* rpre = (const float*)d_in[2];
    const float* apre = (const float*)d_in[3];
    const float* mask = (const float*)d_in[4];
    const int*   nrto = (const int*)d_in[5];

    const int B = in_sizes[0] / HW;            // 64
    const int J = 2 * B;                       // image-ops

    unsigned long long* g_hist = (unsigned long long*)d_ws;
    float* g_pos = (float*)((char*)d_ws + (size_t)J * NBINS * sizeof(unsigned long long));

    const size_t zbytes = (size_t)J * NBINS * sizeof(unsigned long long)
                        + (size_t)J * sizeof(float);
    hipMemsetAsync(d_ws, 0, zbytes, stream);
    hipMemsetAsync(d_out, 0, sizeof(float), stream);

    dim3 grid1(BPI, B);
    maploss_hist<<<grid1, T1, 0, stream>>>(rlab, alab, rpre, apre, mask,
                                           g_hist, g_pos);
    maploss_finalize<<<J, 256, 0, stream>>>(g_hist, g_pos, nrto,
                                            (float*)d_out, B);
}